// Round 8
// baseline (54.780 us; speedup 1.0000x reference)
//
#include <hip/hip_runtime.h>
#include <math.h>
#include <stdint.h>

// DbrxRouter on MI355X:
//   logits = x[8192,6144] @ W^T[6144,16]; softmax; top-4; p=1 renorm.
//   Renorm cancels the softmax denominator -> only top-4 logits needed.
//
// Ledger: R7 = 47.8us, no spill (gll W-staging + runtime chunk loop), but
// grid=512 -> 2 blocks/CU -> 2 waves/SIMD: ~900cy x-load latency vs ~512cy
// compute per chunk left ~15us un-hidden. R8: TOK_PB 16->8 (2 tok/wave,
// acc[32]) -> grid=1024 -> 4 blocks/CU (LDS 33KB allows exactly 4) ->
// 16 waves/CU. Live regs DROP (~85-100), so no spill risk.

constexpr int H       = 6144;
constexpr int E       = 16;
constexpr int HC      = 256;          // floats per chunk per expert (16KB/buf)
constexpr int NCH     = H / HC;       // 24 (even)
constexpr int TPB     = 256;          // 4 waves
constexpr int TOK_PB  = 8;            // 2 tokens per wave, full H per wave
constexpr int T_TOTAL = 8192;

__device__ __forceinline__ void gll16(const float* g, float* l) {
    // global -> LDS direct copy, 16B per lane; dest = wave-uniform base,
    // HW adds lane*16; source is per-lane. __syncthreads() drains vmcnt(0).
    __builtin_amdgcn_global_load_lds(
        (const __attribute__((address_space(1))) uint32_t*)g,
        (__attribute__((address_space(3))) uint32_t*)l,
        16, 0, 0);
}

__global__ __launch_bounds__(TPB, 2)
void dbrx_router(const float* __restrict__ x,
                 const float* __restrict__ w,
                 float* __restrict__ out)
{
    __shared__ float wlds[2][E * HC];   // 2 x 16KB W chunk double-buffer
    __shared__ float lred[4][32];       // [wave][t_loc*16+e] final logits

    const int tid  = threadIdx.x;
    const int wave = tid >> 6;
    const int lane = tid & 63;
    const int tok0 = blockIdx.x * TOK_PB + wave * 2;   // this wave's 2 tokens

    const float* xptr = x + (size_t)tok0 * H + lane * 4;

    float acc[32];                       // [t*16+e], all indices static
    #pragma unroll
    for (int i = 0; i < 32; ++i) acc[i] = 0.f;

    float4 xa[2], xf[2];                 // x ping-pong, static names only

    // ---- prologue: W chunk 0 -> buf0 (gll), x chunk 0 -> xa
    #pragma unroll
    for (int j = 0; j < 4; ++j)
        gll16(w + (size_t)(j * 4 + wave) * H + lane * 4,
              &wlds[0][(j * 4 + wave) * HC]);
    #pragma unroll
    for (int t = 0; t < 2; ++t)
        xa[t] = *reinterpret_cast<const float4*>(xptr + (size_t)t * H);
    __syncthreads();                     // vmcnt drain -> buf0 ready

    // Compute one chunk from wlds[B] with x regs XV (all static indices).
#define COMPUTE(B, XV) do {                                            \
        _Pragma("unroll")                                              \
        for (int eb = 0; eb < 4; ++eb) {                               \
            float4 wv[4];                                              \
            _Pragma("unroll")                                          \
            for (int e = 0; e < 4; ++e)                                \
                wv[e] = *reinterpret_cast<const float4*>(              \
                    &wlds[B][(eb * 4 + e) * HC + lane * 4]);           \
            _Pragma("unroll")                                          \
            for (int t = 0; t < 2; ++t)                                \
                _Pragma("unroll")                                      \
                for (int e = 0; e < 4; ++e) {                          \
                    float s = acc[t * 16 + eb * 4 + e];                \
                    s = fmaf(XV[t].x, wv[e].x, s);                     \
                    s = fmaf(XV[t].y, wv[e].y, s);                     \
                    s = fmaf(XV[t].z, wv[e].z, s);                     \
                    s = fmaf(XV[t].w, wv[e].w, s);                     \
                    acc[t * 16 + eb * 4 + e] = s;                      \
                }                                                      \
        }                                                              \
    } while (0)

    // ---- main loop: runtime loop, 2 steps/iter (static buffer parity).
    for (int cc = 0; cc < NCH; cc += 2) {
        {   // step A: prefetch c+1 -> buf1/xf, compute c from buf0/xa
            #pragma unroll
            for (int j = 0; j < 4; ++j)
                gll16(w + (size_t)(j * 4 + wave) * H + (cc + 1) * HC + lane * 4,
                      &wlds[1][(j * 4 + wave) * HC]);
            #pragma unroll
            for (int t = 0; t < 2; ++t)
                xf[t] = *reinterpret_cast<const float4*>(
                    xptr + (size_t)t * H + (cc + 1) * HC);
            COMPUTE(0, xa);
            __syncthreads();             // buf1 ready; buf0 reads retired
        }
        {   // step B: prefetch c+2 -> buf0/xa, compute c+1 from buf1/xf
            if (cc + 2 < NCH) {
                #pragma unroll
                for (int j = 0; j < 4; ++j)
                    gll16(w + (size_t)(j * 4 + wave) * H + (cc + 2) * HC + lane * 4,
                          &wlds[0][(j * 4 + wave) * HC]);
                #pragma unroll
                for (int t = 0; t < 2; ++t)
                    xa[t] = *reinterpret_cast<const float4*>(
                        xptr + (size_t)t * H + (cc + 2) * HC);
            }
            COMPUTE(1, xf);
            __syncthreads();             // buf0 ready; buf1 reads retired
        }
    }
#undef COMPUTE

    // Reduce-scatter within each 32-lane half (5 static steps): lane l ends
    // holding sum over its half of partial[lane&31]; then one cross-half
    // shfl_xor(32) completes the 64-lane sum. Value idx = lane&31 = t*16+e.
#define RSTEP(S) do {                                                  \
        constexpr int HN = 16 >> (S);                                  \
        const bool hi = (lane & HN) != 0;                              \
        _Pragma("unroll")                                              \
        for (int i = 0; i < HN; ++i) {                                 \
            float send = hi ? acc[i] : acc[i + HN];                    \
            float keep = hi ? acc[i + HN] : acc[i];                    \
            float recv = __shfl_xor(send, HN, 64);                     \
            acc[i] = keep + recv;                                      \
        }                                                              \
    } while (0)
    RSTEP(0); RSTEP(1); RSTEP(2); RSTEP(3); RSTEP(4);
#undef RSTEP
    acc[0] += __shfl_xor(acc[0], 32, 64);   // combine the two 32-lane halves

    if (lane < 32) lred[wave][lane] = acc[0];
    __syncthreads();

    // One thread per token: top-4 (strict > == lowest-index tie-break,
    // matching np/jax) + renormalized exp weights. Token = blk*8 + tid.
    if (tid < TOK_PB) {
        float lg[16];
        #pragma unroll
        for (int e = 0; e < 16; ++e)
            lg[e] = lred[tid >> 1][(tid & 1) * 16 + e];

        float topv[4];
        int   topi[4];
        #pragma unroll
        for (int k = 0; k < 4; ++k) {
            float m = lg[0]; int mi = 0;
            #pragma unroll
            for (int e = 1; e < 16; ++e)
                if (lg[e] > m) { m = lg[e]; mi = e; }
            topv[k] = m; topi[k] = mi;
            #pragma unroll
            for (int e = 0; e < 16; ++e)          // static-index mask-out
                if (e == mi) lg[e] = -INFINITY;
        }

        float ex[4]; float sum = 0.f;
        #pragma unroll
        for (int k = 0; k < 4; ++k) { ex[k] = __expf(topv[k] - topv[0]); sum += ex[k]; }
        const float inv = 1.0f / sum;

        const int tok = blockIdx.x * TOK_PB + tid;
        #pragma unroll
        for (int k = 0; k < 4; ++k) {
            out[(size_t)tok * 4 + k] = ex[k] * inv;                          // top_weights
            out[(size_t)T_TOTAL * 4 + (size_t)tok * 4 + k] = (float)topi[k]; // top_experts
        }
    }
}

extern "C" void kernel_launch(void* const* d_in, const int* in_sizes, int n_in,
                              void* d_out, int out_size, void* d_ws, size_t ws_size,
                              hipStream_t stream) {
    const float* x = (const float*)d_in[0];   // hidden_states [4,2048,6144] fp32
    const float* w = (const float*)d_in[1];   // router_weight [16,6144] fp32
    float* out     = (float*)d_out;           // [8192*4 weights][8192*4 expert ids]
    dbrx_router<<<T_TOTAL / TOK_PB, TPB, 0, stream>>>(x, w, out);
}

// Round 9
// 50.262 us; speedup vs baseline: 1.0899x; 1.0899x over previous
//
#include <hip/hip_runtime.h>
#include <math.h>
#include <stdint.h>

// DbrxRouter on MI355X:
//   logits = x[8192,6144] @ W^T[6144,16]; softmax; top-4; p=1 renorm.
//   Renorm cancels the softmax denominator -> only top-4 logits needed.
//
// Ledger: R7 47.8us = best (gll W-staging, TOK16/TPB256, grid 512 -> 2
// barrier domains/CU). R8 54.8us: TOK8/TPB256 halved FMA:LDS ratio -> LDS
// pipe became co-bottleneck. R9: TPB=128/TOK8 -> 4 blocks/CU with the SAME
// 4 tok/wave ratio as R7; only the barrier-domain count (2->4) changes.
// Each __syncthreads drains vmcnt(0); more independent domains = fewer
// simultaneous HBM-pipe gaps.

constexpr int H       = 6144;
constexpr int E       = 16;
constexpr int HC      = 256;          // floats per chunk per expert (16KB/buf)
constexpr int NCH     = H / HC;       // 24 (even)
constexpr int TPB     = 128;          // 2 waves
constexpr int TOK_PB  = 8;            // 4 tokens per wave, full H per wave
constexpr int T_TOTAL = 8192;

__device__ __forceinline__ void gll16(const float* g, float* l) {
    // global -> LDS direct copy, 16B per lane; dest = wave-uniform base,
    // HW adds lane*16; source is per-lane. __syncthreads() drains vmcnt(0).
    __builtin_amdgcn_global_load_lds(
        (const __attribute__((address_space(1))) uint32_t*)g,
        (__attribute__((address_space(3))) uint32_t*)l,
        16, 0, 0);
}

__global__ __launch_bounds__(TPB, 2)
void dbrx_router(const float* __restrict__ x,
                 const float* __restrict__ w,
                 float* __restrict__ out)
{
    __shared__ float wlds[2][E * HC];   // 2 x 16KB W chunk double-buffer
    __shared__ float lred[2][64];       // [wave][t_loc*16+e] final logits

    const int tid  = threadIdx.x;
    const int wave = tid >> 6;          // 0..1
    const int lane = tid & 63;
    const int tok0 = blockIdx.x * TOK_PB + wave * 4;   // this wave's 4 tokens

    const float* xptr = x + (size_t)tok0 * H + lane * 4;

    float acc[64];                       // [t*16+e], all indices static
    #pragma unroll
    for (int i = 0; i < 64; ++i) acc[i] = 0.f;

    float4 xa[4], xf[4];                 // x ping-pong, static names only

    // W staging with 2 waves: round j (j=0..7) stages expert e = j*2+wave:
    // dest base (j*2+wave)*HC (wave-uniform), src per-lane.
    // ---- prologue: W chunk 0 -> buf0 (gll), x chunk 0 -> xa
    #pragma unroll
    for (int j = 0; j < 8; ++j)
        gll16(w + (size_t)(j * 2 + wave) * H + lane * 4,
              &wlds[0][(j * 2 + wave) * HC]);
    #pragma unroll
    for (int t = 0; t < 4; ++t)
        xa[t] = *reinterpret_cast<const float4*>(xptr + (size_t)t * H);
    __syncthreads();                     // vmcnt drain -> buf0 ready

    // Compute one chunk from wlds[B] with x regs XV (all static indices).
#define COMPUTE(B, XV) do {                                            \
        _Pragma("unroll")                                              \
        for (int eb = 0; eb < 4; ++eb) {                               \
            float4 wv[4];                                              \
            _Pragma("unroll")                                          \
            for (int e = 0; e < 4; ++e)                                \
                wv[e] = *reinterpret_cast<const float4*>(              \
                    &wlds[B][(eb * 4 + e) * HC + lane * 4]);           \
            _Pragma("unroll")                                          \
            for (int t = 0; t < 4; ++t)                                \
                _Pragma("unroll")                                      \
                for (int e = 0; e < 4; ++e) {                          \
                    float s = acc[t * 16 + eb * 4 + e];                \
                    s = fmaf(XV[t].x, wv[e].x, s);                     \
                    s = fmaf(XV[t].y, wv[e].y, s);                     \
                    s = fmaf(XV[t].z, wv[e].z, s);                     \
                    s = fmaf(XV[t].w, wv[e].w, s);                     \
                    acc[t * 16 + eb * 4 + e] = s;                      \
                }                                                      \
        }                                                              \
    } while (0)

    // ---- main loop: runtime loop, 2 steps/iter (static buffer parity).
    for (int cc = 0; cc < NCH; cc += 2) {
        {   // step A: prefetch c+1 -> buf1/xf, compute c from buf0/xa
            #pragma unroll
            for (int j = 0; j < 8; ++j)
                gll16(w + (size_t)(j * 2 + wave) * H + (cc + 1) * HC + lane * 4,
                      &wlds[1][(j * 2 + wave) * HC]);
            #pragma unroll
            for (int t = 0; t < 4; ++t)
                xf[t] = *reinterpret_cast<const float4*>(
                    xptr + (size_t)t * H + (cc + 1) * HC);
            COMPUTE(0, xa);
            __syncthreads();             // buf1 ready; buf0 reads retired
        }
        {   // step B: prefetch c+2 -> buf0/xa, compute c+1 from buf1/xf
            if (cc + 2 < NCH) {
                #pragma unroll
                for (int j = 0; j < 8; ++j)
                    gll16(w + (size_t)(j * 2 + wave) * H + (cc + 2) * HC + lane * 4,
                          &wlds[0][(j * 2 + wave) * HC]);
                #pragma unroll
                for (int t = 0; t < 4; ++t)
                    xa[t] = *reinterpret_cast<const float4*>(
                        xptr + (size_t)t * H + (cc + 2) * HC);
            }
            COMPUTE(1, xf);
            __syncthreads();             // buf0 ready; buf1 reads retired
        }
    }
#undef COMPUTE

    // Butterfly reduce-scatter: 64 partials -> lane l holds fully-reduced
    // acc[l] = logits[tok0+(l>>4)][expert l&15]. Fully static indices.
#define RSTEP(S) do {                                                  \
        constexpr int HN = 32 >> (S);                                  \
        const bool hi = (lane & HN) != 0;                              \
        _Pragma("unroll")                                              \
        for (int i = 0; i < HN; ++i) {                                 \
            float send = hi ? acc[i] : acc[i + HN];                    \
            float keep = hi ? acc[i + HN] : acc[i];                    \
            float recv = __shfl_xor(send, HN, 64);                     \
            acc[i] = keep + recv;                                      \
        }                                                              \
    } while (0)
    RSTEP(0); RSTEP(1); RSTEP(2); RSTEP(3); RSTEP(4); RSTEP(5);
#undef RSTEP

    lred[wave][lane] = acc[0];
    __syncthreads();

    // One thread per token: top-4 (strict > == lowest-index tie-break,
    // matching np/jax) + renormalized exp weights. Token = blk*8 + tid.
    if (tid < TOK_PB) {
        float lg[16];
        #pragma unroll
        for (int e = 0; e < 16; ++e)
            lg[e] = lred[tid >> 2][(tid & 3) * 16 + e];

        float topv[4];
        int   topi[4];
        #pragma unroll
        for (int k = 0; k < 4; ++k) {
            float m = lg[0]; int mi = 0;
            #pragma unroll
            for (int e = 1; e < 16; ++e)
                if (lg[e] > m) { m = lg[e]; mi = e; }
            topv[k] = m; topi[k] = mi;
            #pragma unroll
            for (int e = 0; e < 16; ++e)          // static-index mask-out
                if (e == mi) lg[e] = -INFINITY;
        }

        float ex[4]; float sum = 0.f;
        #pragma unroll
        for (int k = 0; k < 4; ++k) { ex[k] = __expf(topv[k] - topv[0]); sum += ex[k]; }
        const float inv = 1.0f / sum;

        const int tok = blockIdx.x * TOK_PB + tid;
        #pragma unroll
        for (int k = 0; k < 4; ++k) {
            out[(size_t)tok * 4 + k] = ex[k] * inv;                          // top_weights
            out[(size_t)T_TOTAL * 4 + (size_t)tok * 4 + k] = (float)topi[k]; // top_experts
        }
    }
}

extern "C" void kernel_launch(void* const* d_in, const int* in_sizes, int n_in,
                              void* d_out, int out_size, void* d_ws, size_t ws_size,
                              hipStream_t stream) {
    const float* x = (const float*)d_in[0];   // hidden_states [4,2048,6144] fp32
    const float* w = (const float*)d_in[1];   // router_weight [16,6144] fp32
    float* out     = (float*)d_out;           // [8192*4 weights][8192*4 expert ids]
    dbrx_router<<<T_TOTAL / TOK_PB, TPB, 0, stream>>>(x, w, out);
}

// Round 10
// 48.400 us; speedup vs baseline: 1.1318x; 1.0385x over previous
//
#include <hip/hip_runtime.h>
#include <math.h>
#include <stdint.h>

// DbrxRouter on MI355X:
//   logits = x[8192,6144] @ W^T[6144,16]; softmax; top-4; p=1 renorm.
//   Renorm cancels the softmax denominator -> only top-4 logits needed.
//
// Ledger: R7 47.8us best (gll W-staging, TOK16/TPB256/grid512, __syncthreads
// per chunk = vmcnt(0) drain -> ~700cy/chunk of HBM idle). R8/R9 geometry
// probes regressed (W-gll traffic scales with blocks; tok/wave<4 hurts
// FMA:LDS). R10 = R7 geometry + T4 counted waits: issue 8 prefetch ops,
// s_waitcnt vmcnt(8) (own older ops done, newest 8 stay in flight),
// s_barrier, compute, lgkmcnt(0)+s_barrier (WAR fence for next overwrite).

constexpr int H       = 6144;
constexpr int E       = 16;
constexpr int HC      = 256;          // floats per chunk per expert (16KB/buf)
constexpr int NCH     = H / HC;       // 24 (even)
constexpr int TPB     = 256;          // 4 waves
constexpr int TOK_PB  = 16;           // 4 tokens per wave, full H per wave
constexpr int T_TOTAL = 8192;

__device__ __forceinline__ void gll16(const float* g, float* l) {
    // global -> LDS direct copy, 16B per lane; dest = wave-uniform base,
    // HW adds lane*16; source is per-lane. Completion tracked by vmcnt.
    __builtin_amdgcn_global_load_lds(
        (const __attribute__((address_space(1))) uint32_t*)g,
        (__attribute__((address_space(3))) uint32_t*)l,
        16, 0, 0);
}

__global__ __launch_bounds__(TPB, 2)
void dbrx_router(const float* __restrict__ x,
                 const float* __restrict__ w,
                 float* __restrict__ out)
{
    __shared__ float wlds[2][E * HC];   // 2 x 16KB W chunk double-buffer
    __shared__ float lred[4][64];       // [wave][t_loc*16+e] final logits

    const int tid  = threadIdx.x;
    const int wave = tid >> 6;
    const int lane = tid & 63;
    const int tok0 = blockIdx.x * TOK_PB + wave * 4;   // this wave's 4 tokens

    const float* xptr = x + (size_t)tok0 * H + lane * 4;

    float acc[64];                       // [t*16+e], all indices static
    #pragma unroll
    for (int i = 0; i < 64; ++i) acc[i] = 0.f;

    float4 xa[4], xf[4];                 // x ping-pong, static names only

    // ---- prologue: issue chunk 0 staging (4 gll + 4 x loads = 8 vmem ops).
    // No wait here; the first loop step's vmcnt(8) covers it.
    #pragma unroll
    for (int j = 0; j < 4; ++j)
        gll16(w + (size_t)(j * 4 + wave) * H + lane * 4,
              &wlds[0][(j * 4 + wave) * HC]);
    #pragma unroll
    for (int t = 0; t < 4; ++t)
        xa[t] = *reinterpret_cast<const float4*>(xptr + (size_t)t * H);

    // Compute one chunk from wlds[B] with x regs XV (all static indices).
#define COMPUTE(B, XV) do {                                            \
        _Pragma("unroll")                                              \
        for (int eb = 0; eb < 4; ++eb) {                               \
            float4 wv[4];                                              \
            _Pragma("unroll")                                          \
            for (int e = 0; e < 4; ++e)                                \
                wv[e] = *reinterpret_cast<const float4*>(              \
                    &wlds[B][(eb * 4 + e) * HC + lane * 4]);           \
            _Pragma("unroll")                                          \
            for (int t = 0; t < 4; ++t)                                \
                _Pragma("unroll")                                      \
                for (int e = 0; e < 4; ++e) {                          \
                    float s = acc[t * 16 + eb * 4 + e];                \
                    s = fmaf(XV[t].x, wv[e].x, s);                     \
                    s = fmaf(XV[t].y, wv[e].y, s);                     \
                    s = fmaf(XV[t].z, wv[e].z, s);                     \
                    s = fmaf(XV[t].w, wv[e].w, s);                     \
                    acc[t * 16 + eb * 4 + e] = s;                      \
                }                                                      \
        }                                                              \
    } while (0)

    // Counted-wait + raw-barrier pair: own older vmem ops retired, the 8
    // newest (next chunk's prefetch) stay in flight ACROSS the barrier.
#define WAITBAR(NV) do {                                               \
        asm volatile("s_waitcnt vmcnt(" #NV ") lgkmcnt(0)" ::: "memory"); \
        __builtin_amdgcn_s_barrier();                                  \
    } while (0)
    // Post-compute fence: ds_reads of this buffer retired in all waves
    // before anyone overwrites it next step (WAR). lgkmcnt is already
    // drained by FMA consumption; the barrier is the real fence.
#define ENDBAR() do {                                                  \
        asm volatile("s_waitcnt lgkmcnt(0)" ::: "memory");             \
        __builtin_amdgcn_s_barrier();                                  \
    } while (0)

    // ---- main loop: 2 steps/iter (static buffer parity + xa/xf names).
    for (int cc = 0; cc < NCH; cc += 2) {
        {   // step A: c = cc. Prefetch c+1 -> buf1/xf (cc+1 < NCH always).
            #pragma unroll
            for (int j = 0; j < 4; ++j)
                gll16(w + (size_t)(j * 4 + wave) * H + (cc + 1) * HC + lane * 4,
                      &wlds[1][(j * 4 + wave) * HC]);
            #pragma unroll
            for (int t = 0; t < 4; ++t)
                xf[t] = *reinterpret_cast<const float4*>(
                    xptr + (size_t)t * H + (cc + 1) * HC);
            WAITBAR(8);                  // chunk c staged (all waves)
            COMPUTE(0, xa);
            ENDBAR();                    // buf0 reads retired everywhere
        }
        {   // step B: c = cc+1. Prefetch c+2 -> buf0/xa if it exists.
            if (cc + 2 < NCH) {
                #pragma unroll
                for (int j = 0; j < 4; ++j)
                    gll16(w + (size_t)(j * 4 + wave) * H + (cc + 2) * HC + lane * 4,
                          &wlds[0][(j * 4 + wave) * HC]);
                #pragma unroll
                for (int t = 0; t < 4; ++t)
                    xa[t] = *reinterpret_cast<const float4*>(
                        xptr + (size_t)t * H + (cc + 2) * HC);
                WAITBAR(8);              // chunk c staged; c+2 in flight
            } else {
                WAITBAR(0);              // final chunk: full drain
            }
            COMPUTE(1, xf);
            ENDBAR();                    // buf1 reads retired everywhere
        }
    }
#undef COMPUTE
#undef WAITBAR
#undef ENDBAR

    // Butterfly reduce-scatter: 64 partials -> lane l holds fully-reduced
    // acc[l] = logits[tok0+(l>>4)][expert l&15]. Fully static indices.
#define RSTEP(S) do {                                                  \
        constexpr int HN = 32 >> (S);                                  \
        const bool hi = (lane & HN) != 0;                              \
        _Pragma("unroll")                                              \
        for (int i = 0; i < HN; ++i) {                                 \
            float send = hi ? acc[i] : acc[i + HN];                    \
            float keep = hi ? acc[i + HN] : acc[i];                    \
            float recv = __shfl_xor(send, HN, 64);                     \
            acc[i] = keep + recv;                                      \
        }                                                              \
    } while (0)
    RSTEP(0); RSTEP(1); RSTEP(2); RSTEP(3); RSTEP(4); RSTEP(5);
#undef RSTEP

    lred[wave][lane] = acc[0];
    __syncthreads();

    // One thread per token: top-4 (strict > == lowest-index tie-break,
    // matching np/jax) + renormalized exp weights. Token = blk*16 + tid.
    if (tid < TOK_PB) {
        float lg[16];
        #pragma unroll
        for (int e = 0; e < 16; ++e)
            lg[e] = lred[tid >> 2][(tid & 3) * 16 + e];

        float topv[4];
        int   topi[4];
        #pragma unroll
        for (int k = 0; k < 4; ++k) {
            float m = lg[0]; int mi = 0;
            #pragma unroll
            for (int e = 1; e < 16; ++e)
                if (lg[e] > m) { m = lg[e]; mi = e; }
            topv[k] = m; topi[k] = mi;
            #pragma unroll
            for (int e = 0; e < 16; ++e)          // static-index mask-out
                if (e == mi) lg[e] = -INFINITY;
        }

        float ex[4]; float sum = 0.f;
        #pragma unroll
        for (int k = 0; k < 4; ++k) { ex[k] = __expf(topv[k] - topv[0]); sum += ex[k]; }
        const float inv = 1.0f / sum;

        const int tok = blockIdx.x * TOK_PB + tid;
        #pragma unroll
        for (int k = 0; k < 4; ++k) {
            out[(size_t)tok * 4 + k] = ex[k] * inv;                          // top_weights
            out[(size_t)T_TOTAL * 4 + (size_t)tok * 4 + k] = (float)topi[k]; // top_experts
        }
    }
}

extern "C" void kernel_launch(void* const* d_in, const int* in_sizes, int n_in,
                              void* d_out, int out_size, void* d_ws, size_t ws_size,
                              hipStream_t stream) {
    const float* x = (const float*)d_in[0];   // hidden_states [4,2048,6144] fp32
    const float* w = (const float*)d_in[1];   // router_weight [16,6144] fp32
    float* out     = (float*)d_out;           // [8192*4 weights][8192*4 expert ids]
    dbrx_router<<<T_TOTAL / TOK_PB, TPB, 0, stream>>>(x, w, out);
}

// Round 11
// 42.897 us; speedup vs baseline: 1.2770x; 1.1283x over previous
//
#include <hip/hip_runtime.h>
#include <math.h>
#include <stdint.h>

// DbrxRouter on MI355X:
//   logits = x[8192,6144] @ W^T[6144,16]; softmax; top-4; p=1 renorm.
//   Renorm cancels the softmax denominator -> only top-4 logits needed.
//
// Ledger: R7 47.8us (gll W-staging, dbuf, __syncthreads). R10 48.4us
// (counted vmcnt(8), depth-1) -> NEUTRAL: drain wasn't the cost; depth was.
// Per-step period 4800cy vs ~1000cy compute: depth-1 prefetch leaves ~full
// memory latency exposed each step. R11 = depth-2: TRIPLE-buffered W LDS,
// three x reg sets, issue chunk c+2 in step c, wait vmcnt(16) -> loads get
// two full steps to complete. Geometry unchanged (TOK16/TPB256/grid512).

constexpr int H       = 6144;
constexpr int E       = 16;
constexpr int HC      = 256;          // floats per chunk per expert (16KB/buf)
constexpr int NCH     = H / HC;       // 24
constexpr int TPB     = 256;          // 4 waves
constexpr int TOK_PB  = 16;           // 4 tokens per wave, full H per wave
constexpr int T_TOTAL = 8192;

__device__ __forceinline__ void gll16(const float* g, float* l) {
    // global -> LDS direct copy, 16B per lane; dest = wave-uniform base,
    // HW adds lane*16; source is per-lane. Completion tracked by vmcnt.
    __builtin_amdgcn_global_load_lds(
        (const __attribute__((address_space(1))) uint32_t*)g,
        (__attribute__((address_space(3))) uint32_t*)l,
        16, 0, 0);
}

__global__ __launch_bounds__(TPB, 2)
void dbrx_router(const float* __restrict__ x,
                 const float* __restrict__ w,
                 float* __restrict__ out)
{
    __shared__ float wlds[3][E * HC];   // 3 x 16KB W chunk triple-buffer
    __shared__ float lred[4][64];       // [wave][t_loc*16+e] final logits

    const int tid  = threadIdx.x;
    const int wave = tid >> 6;
    const int lane = tid & 63;
    const int tok0 = blockIdx.x * TOK_PB + wave * 4;   // this wave's 4 tokens

    const float* xptr = x + (size_t)tok0 * H + lane * 4;

    float acc[64];                       // [t*16+e], all indices static
    #pragma unroll
    for (int i = 0; i < 64; ++i) acc[i] = 0.f;

    float4 xa[4], xf[4], xg[4];          // x regs for parity 0/1/2 chunks

    // Issue staging for chunk C into LDS buffer B and x reg set XV.
#define ISSUE(C, B, XV) do {                                           \
        _Pragma("unroll")                                              \
        for (int j = 0; j < 4; ++j)                                    \
            gll16(w + (size_t)(j * 4 + wave) * H + (C) * HC + lane * 4,\
                  &wlds[B][(j * 4 + wave) * HC]);                      \
        _Pragma("unroll")                                              \
        for (int t = 0; t < 4; ++t)                                    \
            XV[t] = *reinterpret_cast<const float4*>(                  \
                xptr + (size_t)t * H + (C) * HC);                      \
    } while (0)

    // Compute one chunk from wlds[B] with x regs XV (all static indices).
#define COMPUTE(B, XV) do {                                            \
        _Pragma("unroll")                                              \
        for (int eb = 0; eb < 4; ++eb) {                               \
            float4 wv[4];                                              \
            _Pragma("unroll")                                          \
            for (int e = 0; e < 4; ++e)                                \
                wv[e] = *reinterpret_cast<const float4*>(              \
                    &wlds[B][(eb * 4 + e) * HC + lane * 4]);           \
            _Pragma("unroll")                                          \
            for (int t = 0; t < 4; ++t)                                \
                _Pragma("unroll")                                      \
                for (int e = 0; e < 4; ++e) {                          \
                    float s = acc[t * 16 + eb * 4 + e];                \
                    s = fmaf(XV[t].x, wv[e].x, s);                     \
                    s = fmaf(XV[t].y, wv[e].y, s);                     \
                    s = fmaf(XV[t].z, wv[e].z, s);                     \
                    s = fmaf(XV[t].w, wv[e].w, s);                     \
                    acc[t * 16 + eb * 4 + e] = s;                      \
                }                                                      \
        }                                                              \
    } while (0)

    // Counted wait + barrier: own oldest ops (chunk c) retired; the NV
    // newest (chunks c+1, c+2 staging) stay in flight ACROSS the barrier.
#define WAITBAR(NV) do {                                               \
        asm volatile("s_waitcnt vmcnt(" #NV ") lgkmcnt(0)" ::: "memory"); \
        __builtin_amdgcn_s_barrier();                                  \
    } while (0)
    // Post-compute WAR fence: every wave's ds_reads of this step's buffer
    // retired before any wave's next-step gll can overwrite a buffer.
#define ENDBAR() do {                                                  \
        asm volatile("s_waitcnt lgkmcnt(0)" ::: "memory");             \
        __builtin_amdgcn_s_barrier();                                  \
    } while (0)

    // ---- prologue: chunks 0,1 in flight (16 vmem ops/thread)
    ISSUE(0, 0, xa);
    ISSUE(1, 1, xf);

    // ---- main loop: 3 steps/iter, static parity. Step computing chunk c
    // (parity p=c%3) issues chunk c+2 into buf/(x-set) (p+2)%3.
    for (int cc = 0; cc <= 18; cc += 3) {   // steps c = 0..20
        ISSUE(cc + 2, 2, xg); WAITBAR(16); COMPUTE(0, xa); ENDBAR();
        ISSUE(cc + 3, 0, xa); WAITBAR(16); COMPUTE(1, xf); ENDBAR();
        ISSUE(cc + 4, 1, xf); WAITBAR(16); COMPUTE(2, xg); ENDBAR();
    }
    // ---- tail: steps 21, 22, 23
    ISSUE(23, 2, xg); WAITBAR(16); COMPUTE(0, xa); ENDBAR();   // c=21
    WAITBAR(8);  COMPUTE(1, xf); ENDBAR();                     // c=22
    WAITBAR(0);  COMPUTE(2, xg);                               // c=23
#undef ISSUE
#undef COMPUTE
#undef WAITBAR
#undef ENDBAR

    // Butterfly reduce-scatter: 64 partials -> lane l holds fully-reduced
    // acc[l] = logits[tok0+(l>>4)][expert l&15]. Fully static indices.
#define RSTEP(S) do {                                                  \
        constexpr int HN = 32 >> (S);                                  \
        const bool hi = (lane & HN) != 0;                              \
        _Pragma("unroll")                                              \
        for (int i = 0; i < HN; ++i) {                                 \
            float send = hi ? acc[i] : acc[i + HN];                    \
            float keep = hi ? acc[i + HN] : acc[i];                    \
            float recv = __shfl_xor(send, HN, 64);                     \
            acc[i] = keep + recv;                                      \
        }                                                              \
    } while (0)
    RSTEP(0); RSTEP(1); RSTEP(2); RSTEP(3); RSTEP(4); RSTEP(5);
#undef RSTEP

    lred[wave][lane] = acc[0];
    __syncthreads();

    // One thread per token: top-4 (strict > == lowest-index tie-break,
    // matching np/jax) + renormalized exp weights. Token = blk*16 + tid.
    if (tid < TOK_PB) {
        float lg[16];
        #pragma unroll
        for (int e = 0; e < 16; ++e)
            lg[e] = lred[tid >> 2][(tid & 3) * 16 + e];

        float topv[4];
        int   topi[4];
        #pragma unroll
        for (int k = 0; k < 4; ++k) {
            float m = lg[0]; int mi = 0;
            #pragma unroll
            for (int e = 1; e < 16; ++e)
                if (lg[e] > m) { m = lg[e]; mi = e; }
            topv[k] = m; topi[k] = mi;
            #pragma unroll
            for (int e = 0; e < 16; ++e)          // static-index mask-out
                if (e == mi) lg[e] = -INFINITY;
        }

        float ex[4]; float sum = 0.f;
        #pragma unroll
        for (int k = 0; k < 4; ++k) { ex[k] = __expf(topv[k] - topv[0]); sum += ex[k]; }
        const float inv = 1.0f / sum;

        const int tok = blockIdx.x * TOK_PB + tid;
        #pragma unroll
        for (int k = 0; k < 4; ++k) {
            out[(size_t)tok * 4 + k] = ex[k] * inv;                          // top_weights
            out[(size_t)T_TOTAL * 4 + (size_t)tok * 4 + k] = (float)topi[k]; // top_experts
        }
    }
}

extern "C" void kernel_launch(void* const* d_in, const int* in_sizes, int n_in,
                              void* d_out, int out_size, void* d_ws, size_t ws_size,
                              hipStream_t stream) {
    const float* x = (const float*)d_in[0];   // hidden_states [4,2048,6144] fp32
    const float* w = (const float*)d_in[1];   // router_weight [16,6144] fp32
    float* out     = (float*)d_out;           // [8192*4 weights][8192*4 expert ids]
    dbrx_router<<<T_TOTAL / TOK_PB, TPB, 0, stream>>>(x, w, out);
}

// Round 12
// 40.800 us; speedup vs baseline: 1.3426x; 1.0514x over previous
//
#include <hip/hip_runtime.h>
#include <math.h>
#include <stdint.h>

// DbrxRouter on MI355X:
//   logits = x[8192,6144] @ W^T[6144,16]; softmax; top-4; p=1 renorm.
//   Renorm cancels the softmax denominator -> only top-4 logits needed.
//
// Ledger: R7 47.8 (dbuf + __syncthreads); R10 48.4 (counted vmcnt, depth-1,
// neutral); R11 42.9 (depth-2 triple-buffer, 2 barriers/step). Per-step
// period 4300cy vs ~3300cy memory service: residual = 2-barrier convoy.
// R12 = single barrier per step: {wait vmcnt(8) lgkm(0); s_barrier;
// COMPUTE(c); ISSUE(c+2)}. Barrier both publishes chunk c (each wave
// waited own staging) and WAR-fences the buf[(c-1)%3] overwrite (reads
// pre-dated previous barrier). 25 barriers instead of 48.

constexpr int H       = 6144;
constexpr int E       = 16;
constexpr int HC      = 256;          // floats per chunk per expert (16KB/buf)
constexpr int NCH     = H / HC;       // 24
constexpr int TPB     = 256;          // 4 waves
constexpr int TOK_PB  = 16;           // 4 tokens per wave, full H per wave
constexpr int T_TOTAL = 8192;

__device__ __forceinline__ void gll16(const float* g, float* l) {
    // global -> LDS direct copy, 16B per lane; dest = wave-uniform base,
    // HW adds lane*16; source is per-lane. Completion tracked by vmcnt.
    __builtin_amdgcn_global_load_lds(
        (const __attribute__((address_space(1))) uint32_t*)g,
        (__attribute__((address_space(3))) uint32_t*)l,
        16, 0, 0);
}

__global__ __launch_bounds__(TPB, 2)
void dbrx_router(const float* __restrict__ x,
                 const float* __restrict__ w,
                 float* __restrict__ out)
{
    __shared__ float wlds[3][E * HC];   // 3 x 16KB W chunk triple-buffer
    __shared__ float lred[4][64];       // [wave][t_loc*16+e] final logits

    const int tid  = threadIdx.x;
    const int wave = tid >> 6;
    const int lane = tid & 63;
    const int tok0 = blockIdx.x * TOK_PB + wave * 4;   // this wave's 4 tokens

    const float* xptr = x + (size_t)tok0 * H + lane * 4;

    float acc[64];                       // [t*16+e], all indices static
    #pragma unroll
    for (int i = 0; i < 64; ++i) acc[i] = 0.f;

    float4 xa[4], xf[4], xg[4];          // x regs for parity 0/1/2 chunks

    // Issue staging for chunk C into LDS buffer B and x reg set XV.
#define ISSUE(C, B, XV) do {                                           \
        _Pragma("unroll")                                              \
        for (int j = 0; j < 4; ++j)                                    \
            gll16(w + (size_t)(j * 4 + wave) * H + (C) * HC + lane * 4,\
                  &wlds[B][(j * 4 + wave) * HC]);                      \
        _Pragma("unroll")                                              \
        for (int t = 0; t < 4; ++t)                                    \
            XV[t] = *reinterpret_cast<const float4*>(                  \
                xptr + (size_t)t * H + (C) * HC);                      \
    } while (0)

    // Compute one chunk from wlds[B] with x regs XV (all static indices).
#define COMPUTE(B, XV) do {                                            \
        _Pragma("unroll")                                              \
        for (int eb = 0; eb < 4; ++eb) {                               \
            float4 wv[4];                                              \
            _Pragma("unroll")                                          \
            for (int e = 0; e < 4; ++e)                                \
                wv[e] = *reinterpret_cast<const float4*>(              \
                    &wlds[B][(eb * 4 + e) * HC + lane * 4]);           \
            _Pragma("unroll")                                          \
            for (int t = 0; t < 4; ++t)                                \
                _Pragma("unroll")                                      \
                for (int e = 0; e < 4; ++e) {                          \
                    float s = acc[t * 16 + eb * 4 + e];                \
                    s = fmaf(XV[t].x, wv[e].x, s);                     \
                    s = fmaf(XV[t].y, wv[e].y, s);                     \
                    s = fmaf(XV[t].z, wv[e].z, s);                     \
                    s = fmaf(XV[t].w, wv[e].w, s);                     \
                    acc[t * 16 + eb * 4 + e] = s;                      \
                }                                                      \
        }                                                              \
    } while (0)

    // Single barrier per step. vmcnt(8): chunk c's 8 ops retired (only
    // chunk c+1's 8 may remain in flight); lgkmcnt(0): this wave's LDS
    // reads of the to-be-overwritten buffer are retired. The barrier then
    // makes both globally true before COMPUTE reads / ISSUE overwrites.
#define STEPBAR(NV) do {                                               \
        asm volatile("s_waitcnt vmcnt(" #NV ") lgkmcnt(0)" ::: "memory"); \
        __builtin_amdgcn_s_barrier();                                  \
    } while (0)

    // ---- prologue: chunks 0,1 in flight (16 vmem ops/thread)
    ISSUE(0, 0, xa);
    ISSUE(1, 1, xf);

    // ---- main loop: 3 steps/iter, static parity. Step c: wait+barrier,
    // compute chunk c from buf c%3, issue chunk c+2 into buf (c+2)%3.
    for (int cc = 0; cc < 21; cc += 3) {   // 7 iters: steps c = 0..20
        STEPBAR(8); COMPUTE(0, xa); ISSUE(cc + 2, 2, xg);
        STEPBAR(8); COMPUTE(1, xf); ISSUE(cc + 3, 0, xa);
        STEPBAR(8); COMPUTE(2, xg); ISSUE(cc + 4, 1, xf);
    }
    // ---- tail: steps 21, 22, 23
    STEPBAR(8); COMPUTE(0, xa); ISSUE(23, 2, xg);   // c=21
    STEPBAR(8); COMPUTE(1, xf);                     // c=22
    STEPBAR(0); COMPUTE(2, xg);                     // c=23
#undef ISSUE
#undef COMPUTE
#undef STEPBAR

    // Butterfly reduce-scatter: 64 partials -> lane l holds fully-reduced
    // acc[l] = logits[tok0+(l>>4)][expert l&15]. Fully static indices.
#define RSTEP(S) do {                                                  \
        constexpr int HN = 32 >> (S);                                  \
        const bool hi = (lane & HN) != 0;                              \
        _Pragma("unroll")                                              \
        for (int i = 0; i < HN; ++i) {                                 \
            float send = hi ? acc[i] : acc[i + HN];                    \
            float keep = hi ? acc[i + HN] : acc[i];                    \
            float recv = __shfl_xor(send, HN, 64);                     \
            acc[i] = keep + recv;                                      \
        }                                                              \
    } while (0)
    RSTEP(0); RSTEP(1); RSTEP(2); RSTEP(3); RSTEP(4); RSTEP(5);
#undef RSTEP

    lred[wave][lane] = acc[0];
    __syncthreads();

    // One thread per token: top-4 (strict > == lowest-index tie-break,
    // matching np/jax) + renormalized exp weights. Token = blk*16 + tid.
    if (tid < TOK_PB) {
        float lg[16];
        #pragma unroll
        for (int e = 0; e < 16; ++e)
            lg[e] = lred[tid >> 2][(tid & 3) * 16 + e];

        float topv[4];
        int   topi[4];
        #pragma unroll
        for (int k = 0; k < 4; ++k) {
            float m = lg[0]; int mi = 0;
            #pragma unroll
            for (int e = 1; e < 16; ++e)
                if (lg[e] > m) { m = lg[e]; mi = e; }
            topv[k] = m; topi[k] = mi;
            #pragma unroll
            for (int e = 0; e < 16; ++e)          // static-index mask-out
                if (e == mi) lg[e] = -INFINITY;
        }

        float ex[4]; float sum = 0.f;
        #pragma unroll
        for (int k = 0; k < 4; ++k) { ex[k] = __expf(topv[k] - topv[0]); sum += ex[k]; }
        const float inv = 1.0f / sum;

        const int tok = blockIdx.x * TOK_PB + tid;
        #pragma unroll
        for (int k = 0; k < 4; ++k) {
            out[(size_t)tok * 4 + k] = ex[k] * inv;                          // top_weights
            out[(size_t)T_TOTAL * 4 + (size_t)tok * 4 + k] = (float)topi[k]; // top_experts
        }
    }
}

extern "C" void kernel_launch(void* const* d_in, const int* in_sizes, int n_in,
                              void* d_out, int out_size, void* d_ws, size_t ws_size,
                              hipStream_t stream) {
    const float* x = (const float*)d_in[0];   // hidden_states [4,2048,6144] fp32
    const float* w = (const float*)d_in[1];   // router_weight [16,6144] fp32
    float* out     = (float*)d_out;           // [8192*4 weights][8192*4 expert ids]
    dbrx_router<<<T_TOTAL / TOK_PB, TPB, 0, stream>>>(x, w, out);
}